// Round 7
// baseline (7655.647 us; speedup 1.0000x reference)
//
#include <hip/hip_runtime.h>
#include <math.h>

// Problem constants
constexpr int B_ = 4096;
constexpr int T_ = 20;
constexpr int XD = 256;   // X_DIM
constexpr int ZD = 128;   // Z_DIM
constexpr int HD = 512;   // H_DIM
constexpr int DD = 384;   // X+Z

constexpr int NBLK = 512; // megakernel grid (2 blocks/CU co-resident)

using short8 = __attribute__((ext_vector_type(8))) short;
using bf16x8 = __attribute__((ext_vector_type(8))) __bf16;
using f32x4  = __attribute__((ext_vector_type(4))) float;

__device__ __forceinline__ float lrelu_f(float v) { return v > 0.f ? v : 0.2f * v; }
__device__ __forceinline__ float softplus_f(float v) {
    return log1pf(expf(-fabsf(v))) + fmaxf(v, 0.f);
}
__device__ __forceinline__ float sigmoid_f(float v) { return 1.f / (1.f + expf(-v)); }

// float -> bf16 (round to nearest even), finite inputs
__device__ __forceinline__ unsigned short f2b(float f) {
    unsigned u = __builtin_bit_cast(unsigned, f);
    u += 0x7fff + ((u >> 16) & 1);
    return (unsigned short)(u >> 16);
}

__device__ __forceinline__ f32x4 mfma16(short8 a, short8 b, f32x4 c) {
    return __builtin_amdgcn_mfma_f32_16x16x32_bf16(
        __builtin_bit_cast(bf16x8, a), __builtin_bit_cast(bf16x8, b), c, 0, 0, 0);
}

// async global->LDS, 16 B per lane; lds base must be wave-uniform
__device__ __forceinline__ void load_lds16(const unsigned short* g, unsigned short* l) {
    __builtin_amdgcn_global_load_lds(
        (const __attribute__((address_space(1))) unsigned int*)g,
        (__attribute__((address_space(3))) unsigned int*)l,
        16, 0, 0);
}

// device-scope grid barrier (monotonic counter; all NBLK blocks co-resident)
__device__ __forceinline__ void gbar(unsigned* cnt, unsigned target) {
    __syncthreads();
    if (threadIdx.x == 0) {
        __threadfence();   // release: prior global writes visible agent-wide
        __hip_atomic_fetch_add(cnt, 1u, __ATOMIC_RELEASE, __HIP_MEMORY_SCOPE_AGENT);
        while (__hip_atomic_load(cnt, __ATOMIC_RELAXED, __HIP_MEMORY_SCOPE_AGENT) < target)
            __builtin_amdgcn_s_sleep(2);
        __threadfence();   // acquire: invalidate L1/L2 before consuming remote writes
    }
    __syncthreads();
}

// ---------------------------------------------------------------------------
// MTx128-tile bf16 MFMA GEMM core (MT in {64,128}), counted-vmcnt pipeline:
//   C[MT,128] += A1[MT,K1] @ W1[128,K1]^T + A2[MT,K2] @ W2[128,K2]^T
// BK=32, double-buffered LDS. Per wave per K-tile: LPT = MT/64+2 loads.
// Chunk swizzle c' = c ^ ((row>>1)&3) on global source AND ds_read (rule #21).
// K1,K2 multiples of 32 (K2 may be 0), K1+K2 >= 64; lda/ldw multiples of 8.
// acc[mi][ni][r]: row = bm + (wave>>1)*(MT/2) + mi*16 + (lane>>4)*4 + r,
//                 col = bn + (wave&1)*64 + ni*16 + (lane&15)
// ---------------------------------------------------------------------------
template <int MT>
__device__ __forceinline__ void gemm_core(
    const unsigned short* A1, int lda1, int K1,
    const unsigned short* A2, int lda2, int K2,
    const unsigned short* W1, int ldw1,
    const unsigned short* W2, int ldw2,
    int bm, int bn,
    unsigned short* As, unsigned short* Bs,
    f32x4 (&acc)[MT / 32][4])
{
    constexpr int MI   = MT / 32;     // m-fragments per wave
    constexpr int WRS  = MT / 2;      // rows per wave-row-group
    constexpr int NA   = MT / 64;     // A staging rounds (1 or 2)
    constexpr int LPT  = NA + 2;      // per-wave global_load_lds per K-tile
    constexpr int ABUF = MT * 32;     // shorts per A buffer

    const int tid  = threadIdx.x;
    const int lane = tid & 63;
    const int wave = tid >> 6;
    const int wr = wave >> 1, wc = wave & 1;
    const int fr = lane & 15, fg = lane >> 4;
    const int cswz = fg ^ ((fr >> 1) & 3);      // read-side chunk swizzle

    const int r0 = tid >> 2,          c0 = (tid & 3) ^ ((r0 >> 1) & 3);
    const int r1 = (256 + tid) >> 2,  c1 = ((256 + tid) & 3) ^ ((r1 >> 1) & 3);

    const int n1 = K1 / 32;
    const int nt = n1 + K2 / 32;

    auto stage = [&](int i, int buf) {
        const unsigned short* Ag;
        const unsigned short* Wg;
        int lda, ldw, kb;
        if (i < n1) { Ag = A1; Wg = W1; lda = lda1; ldw = ldw1; kb = i * 32; }
        else        { Ag = A2; Wg = W2; lda = lda2; ldw = ldw2; kb = (i - n1) * 32; }
        unsigned short* lA = As + buf * ABUF + wave * 512;   // wave-uniform bases
        unsigned short* lB = Bs + buf * 4096 + wave * 512;
        load_lds16(Ag + (size_t)(bm + r0) * lda + kb + c0 * 8, lA);
        if constexpr (NA == 2)
            load_lds16(Ag + (size_t)(bm + r1) * lda + kb + c1 * 8, lA + 2048);
        load_lds16(Wg + (size_t)(bn + r0) * ldw + kb + c0 * 8, lB);
        load_lds16(Wg + (size_t)(bn + r1) * ldw + kb + c1 * 8, lB + 2048);
    };

    auto compute = [&](int buf) {
        const unsigned short* Ab_ = As + buf * ABUF;
        const unsigned short* Bb_ = Bs + buf * 4096;
        short8 af[MI], bv[4];
#pragma unroll
        for (int mi = 0; mi < MI; ++mi)
            af[mi] = *reinterpret_cast<const short8*>(Ab_ + (wr * WRS + mi * 16 + fr) * 32 + cswz * 8);
#pragma unroll
        for (int ni = 0; ni < 4; ++ni)
            bv[ni] = *reinterpret_cast<const short8*>(Bb_ + (wc * 64 + ni * 16 + fr) * 32 + cswz * 8);
#pragma unroll
        for (int mi = 0; mi < MI; ++mi)
#pragma unroll
            for (int ni = 0; ni < 4; ++ni)
                acc[mi][ni] = mfma16(af[mi], bv[ni], acc[mi][ni]);
    };

    // prologue: tiles 0 and 1 in flight (2*LPT outstanding per wave)
    stage(0, 0);
    stage(1, 1);
    if constexpr (LPT == 4) asm volatile("s_waitcnt vmcnt(4)" ::: "memory");
    else                    asm volatile("s_waitcnt vmcnt(3)" ::: "memory");
    __builtin_amdgcn_s_barrier();

    for (int i = 0; i < nt; ++i) {
        compute(i & 1);
        if (i + 1 < nt) {
            asm volatile("" ::: "memory");             // reads stay before barrier
            __builtin_amdgcn_s_barrier();              // all waves done reading buf
            if (i + 2 < nt) {
                stage(i + 2, i & 1);                   // refill freed buffer
                if constexpr (LPT == 4) asm volatile("s_waitcnt vmcnt(4)" ::: "memory");
                else                    asm volatile("s_waitcnt vmcnt(3)" ::: "memory");
            } else {
                asm volatile("s_waitcnt vmcnt(0)" ::: "memory");  // last tile
            }
            __builtin_amdgcn_s_barrier();
        }
    }
}

// ---------------------------------------------------------------------------
// Persistent megakernel: the entire 20-step loop; 4 phases/step separated by
// device-scope grid barriers. NBLK=512 blocks, 2 blocks/CU co-resident.
// ---------------------------------------------------------------------------
__global__ __launch_bounds__(256, 2) void k_steps(
    const unsigned short* __restrict__ xball,
    unsigned short* __restrict__ hb0,
    unsigned short* __restrict__ hb1,
    unsigned short* __restrict__ umuvb,
    unsigned short* __restrict__ meanb,
    unsigned short* __restrict__ phib,
    const unsigned short* __restrict__ Wub,
    const unsigned short* __restrict__ Wmlvb,
    const unsigned short* __restrict__ Wcb,
    const unsigned short* __restrict__ Wrih,
    const unsigned short* __restrict__ Wrhh,
    const float* __restrict__ bu,
    const float* __restrict__ bmlv,
    const float* __restrict__ br,
    const float* __restrict__ bphi,
    float* __restrict__ c,
    float* __restrict__ out_z, float* __restrict__ out_mean,
    float* __restrict__ out_lv, float* __restrict__ out_hout,
    float* __restrict__ out_hlo,
    unsigned* __restrict__ bar)
{
    __shared__ unsigned short As[4096];   // MT=64: 2 bufs x 2048 shorts (8 KB)
    __shared__ unsigned short Bs[8192];   // 2 bufs x 4096 shorts (16 KB)

    const int blk = blockIdx.x;
    const int tid = threadIdx.x, lane = tid & 63, wave = tid >> 6;
    const int wr = wave >> 1, wc = wave & 1, fr = lane & 15, rg = lane >> 4;
    unsigned bidx = 0;

#pragma unroll 1
    for (int t = 0; t < T_; ++t) {
        const unsigned short* hbt = (t & 1) ? hb1 : hb0;   // h_t (read)
        unsigned short* hbn = (t & 1) ? hb0 : hb1;         // h_{t+1} (write)
        const unsigned short* xb = xball + (size_t)t * B_ * XD;

        // ---- phase 1: [u_m|u_v] = lrelu([x,h]@Wub^T + bu)  (512 jobs) ----
        {
            const int bn = (blk & 7) * 128, bm = (blk >> 3) * 64;
            f32x4 acc[2][4] = {};
            gemm_core<64>(xb, XD, XD, hbt, HD, HD,
                          Wub, XD + HD, Wub + XD, XD + HD, bm, bn, As, Bs, acc);
            float bb[4];
#pragma unroll
            for (int ni = 0; ni < 4; ++ni)
                bb[ni] = bu[bn + wc * 64 + ni * 16 + fr];
#pragma unroll
            for (int mi = 0; mi < 2; ++mi)
#pragma unroll
                for (int r = 0; r < 4; ++r) {
                    const int row = bm + wr * 32 + mi * 16 + rg * 4 + r;
#pragma unroll
                    for (int ni = 0; ni < 4; ++ni) {
                        const int col = bn + wc * 64 + ni * 16 + fr;
                        umuvb[(size_t)row * 1024 + col] = f2b(lrelu_f(acc[mi][ni][r] + bb[ni]));
                    }
                }
        }
        gbar(bar, ++bidx * NBLK);

        // ---- phase 2: mean/logvar (block-diag W, 128 jobs) ----
        if (blk < 128) {
            const int bn = (blk & 1) * 128, bm = (blk >> 1) * 64;
            f32x4 acc[2][4] = {};
            gemm_core<64>(umuvb, 1024, 1024, umuvb, 1024, 0,
                          Wmlvb, 1024, Wmlvb, 1024, bm, bn, As, Bs, acc);
            float bb[4];
#pragma unroll
            for (int ni = 0; ni < 4; ++ni)
                bb[ni] = bmlv[bn + wc * 64 + ni * 16 + fr];
#pragma unroll
            for (int mi = 0; mi < 2; ++mi)
#pragma unroll
                for (int r = 0; r < 4; ++r) {
                    const int row = bm + wr * 32 + mi * 16 + rg * 4 + r;
#pragma unroll
                    for (int ni = 0; ni < 4; ++ni) {
                        const int col = bn + wc * 64 + ni * 16 + fr;
                        const float v = lrelu_f(acc[mi][ni][r] + bb[ni]);
                        if (bn == 0) {   // mean half
                            const size_t o = (size_t)row * (T_ * ZD) + (size_t)t * ZD + col;
                            out_z[o] = v; out_mean[o] = v;
                            meanb[(size_t)row * ZD + col] = f2b(v);
                        } else {         // logvar half
                            out_lv[(size_t)row * (T_ * ZD) + (size_t)t * ZD + (col - 128)] = v;
                        }
                    }
                }
        }
        gbar(bar, ++bidx * NBLK);

        // ---- phase 3: phi = softplus(lrelu([x,mean]@Wc^T + bphi)) (512 jobs) ----
        {
            const int bn = (blk & 7) * 128, bm = (blk >> 3) * 64;
            f32x4 acc[2][4] = {};
            gemm_core<64>(xb, XD, XD, meanb, ZD, ZD,
                          Wcb, DD, Wcb + XD, DD, bm, bn, As, Bs, acc);
            float bb[4];
#pragma unroll
            for (int ni = 0; ni < 4; ++ni)
                bb[ni] = bphi[bn + wc * 64 + ni * 16 + fr];
#pragma unroll
            for (int mi = 0; mi < 2; ++mi)
#pragma unroll
                for (int r = 0; r < 4; ++r) {
                    const int row = bm + wr * 32 + mi * 16 + rg * 4 + r;
#pragma unroll
                    for (int ni = 0; ni < 4; ++ni) {
                        const int col = bn + wc * 64 + ni * 16 + fr;
                        phib[(size_t)row * 1024 + col] = f2b(softplus_f(lrelu_f(acc[mi][ni][r] + bb[ni])));
                    }
                }
        }
        gbar(bar, ++bidx * NBLK);

        // ---- phase 4: gates (gate-interleaved) + fused LSTM (1024 jobs, 2/block) ----
#pragma unroll 1
        for (int j = 0; j < 2; ++j) {
            if (j) __syncthreads();   // protect LDS between back-to-back jobs
            const int job = blk * 2 + j;
            const int bn = (job & 15) * 128, bm = (job >> 4) * 64;
            f32x4 acc[2][4] = {};
            gemm_core<64>(phib, 1024, 1024, hbt, HD, HD,
                          Wrih, 1024, Wrhh, HD, bm, bn, As, Bs, acc);
            const int n = ((bn + wc * 64) >> 6) * 16 + fr;   // hidden unit
            float bb[4];
#pragma unroll
            for (int ni = 0; ni < 4; ++ni)
                bb[ni] = br[bn + wc * 64 + ni * 16 + fr];
#pragma unroll
            for (int mi = 0; mi < 2; ++mi)
#pragma unroll
                for (int r = 0; r < 4; ++r) {
                    const int row = bm + wr * 32 + mi * 16 + rg * 4 + r;
                    const size_t idx = (size_t)row * HD + n;
                    const float gi = acc[mi][0][r] + bb[0];
                    const float gf = acc[mi][1][r] + bb[1];
                    const float gg = acc[mi][2][r] + bb[2];
                    const float go = acc[mi][3][r] + bb[3];
                    const float co = c[idx];
                    const float cn = sigmoid_f(gf) * co + sigmoid_f(gi) * tanhf(gg);
                    const float hn = sigmoid_f(go) * tanhf(cn);
                    c[idx] = cn;
                    hbn[idx] = f2b(hn);
                    const size_t ob = (size_t)row * (T_ * HD) + n;
                    out_hlo[ob + (size_t)t * HD] = hn;                 // h after update
                    if (t + 1 < T_)
                        out_hout[ob + (size_t)(t + 1) * HD] = hn;      // h BEFORE update at t+1
                }
        }
        gbar(bar, ++bidx * NBLK);
    }
}

// ---------------------------------------------------------------------------
// prep GEMM (MT=128 core) for Wc = Wphi @ A
__global__ __launch_bounds__(256) void k_gemm_plain(
    const unsigned short* __restrict__ A1, int lda1, int K1,
    const unsigned short* __restrict__ W1, int ldw1,
    unsigned short* __restrict__ DB, int lddb)
{
    __shared__ unsigned short As[8192];
    __shared__ unsigned short Bs[8192];
    const int bm = blockIdx.y * 128, bn = blockIdx.x * 128;
    f32x4 acc[4][4] = {};
    gemm_core<128>(A1, lda1, K1, A1, lda1, 0, W1, ldw1, W1, ldw1, bm, bn, As, Bs, acc);

    const int tid = threadIdx.x, lane = tid & 63, wave = tid >> 6;
    const int wr = wave >> 1, wc = wave & 1, fr = lane & 15, rg = lane >> 4;
#pragma unroll
    for (int mi = 0; mi < 4; ++mi)
#pragma unroll
        for (int r = 0; r < 4; ++r) {
            const int row = bm + wr * 64 + mi * 16 + rg * 4 + r;
#pragma unroll
            for (int ni = 0; ni < 4; ++ni) {
                const int col = bn + wc * 64 + ni * 16 + fr;
                DB[(size_t)row * lddb + col] = f2b(acc[mi][ni][r]);
            }
        }
}

// init: c = 0, hb0 = 0, out_hout[:, 0, :] = 0, barrier counter = 0
__global__ __launch_bounds__(256) void init_state(
    float* __restrict__ c, unsigned short* __restrict__ hb,
    float* __restrict__ oh0, unsigned* __restrict__ bar)
{
    const int i = blockIdx.x * 256 + threadIdx.x;   // B_*HD
    c[i] = 0.f; hb[i] = 0;
    const int b = i >> 9, nn = i & 511;
    oh0[(size_t)b * (T_ * HD) + nn] = 0.f;
    if (i == 0) *bar = 0u;
}

__global__ __launch_bounds__(256) void f32_to_bf16(
    const float* __restrict__ src, unsigned short* __restrict__ dst, int n4)
{
    const int i = blockIdx.x * 256 + threadIdx.x;
    if (i >= n4) return;
    float4 v = reinterpret_cast<const float4*>(src)[i];
    ushort4 o;
    o.x = f2b(v.x); o.y = f2b(v.y); o.z = f2b(v.z); o.w = f2b(v.w);
    reinterpret_cast<ushort4*>(dst)[i] = o;
}

// all x slices: x [B][T][XD] fp32 -> xball [T][B][XD] bf16 (row = t*B+b)
__global__ __launch_bounds__(256) void conv_x_all(
    const float* __restrict__ x, unsigned short* __restrict__ xball)
{
    const int i = blockIdx.x * 256 + threadIdx.x;   // < B_*T_*XD/4
    const int d = i & 63;                           // float4 within row
    const int bt = i >> 6;
    const int b = bt / T_, t = bt % T_;
    float4 v = reinterpret_cast<const float4*>(x)[i];
    ushort4 o;
    o.x = f2b(v.x); o.y = f2b(v.y); o.z = f2b(v.z); o.w = f2b(v.w);
    reinterpret_cast<ushort4*>(xball)[((size_t)t * B_ + b) * (XD / 4) + d] = o;
}

// Wub[1024][768] = [Wm1; Wv1] (bf16)
__global__ __launch_bounds__(256) void prep_wu(
    const float* __restrict__ Wm1, const float* __restrict__ Wv1,
    unsigned short* __restrict__ Wub)
{
    const int k = blockIdx.x * 256 + threadIdx.x;   // 0..767
    const int nrow = blockIdx.y;                    // 0..1023
    const float v = nrow < 512 ? Wm1[nrow * 768 + k] : Wv1[(nrow - 512) * 768 + k];
    Wub[nrow * 768 + k] = f2b(v);
}

// Wmlv[256][1024] block-diagonal: [Wm2 0; 0 Wv2] (bf16)
__global__ __launch_bounds__(256) void prep_wmlv(
    const float* __restrict__ Wm2, const float* __restrict__ Wv2,
    unsigned short* __restrict__ Wmlv)
{
    const int k = blockIdx.x * 256 + threadIdx.x;   // 0..1023
    const int cc = blockIdx.y;                      // 0..255
    float v = 0.f;
    if (cc < 128) { if (k < 512) v = Wm2[cc * 512 + k]; }
    else          { if (k >= 512) v = Wv2[(cc - 128) * 512 + (k - 512)]; }
    Wmlv[cc * 1024 + k] = f2b(v);
}

// gate-interleaved reorder of W_ih, W_hh
__global__ __launch_bounds__(256) void prep_wg(
    const float* __restrict__ Wih, const float* __restrict__ Whh,
    unsigned short* __restrict__ Wrih, unsigned short* __restrict__ Wrhh)
{
    const int cc = blockIdx.y;                      // 0..2047
    const int gate = (cc >> 4) & 3;
    const int n = ((cc >> 6) << 4) + (cc & 15);
    const int orig = gate * 512 + n;
    const int kk = blockIdx.x * 256 + threadIdx.x;  // 0..1535
    if (kk < 1024) Wrih[(size_t)cc * 1024 + kk] = f2b(Wih[(size_t)orig * 1024 + kk]);
    else           Wrhh[(size_t)cc * 512 + (kk - 1024)] = f2b(Whh[(size_t)orig * 512 + (kk - 1024)]);
}

// At[k][j] = bf16(A[j][k])  (A is [384][384] fp32 row-major)
__global__ __launch_bounds__(256) void prep_at(
    const float* __restrict__ A, unsigned short* __restrict__ At)
{
    const int i = blockIdx.x * 256 + threadIdx.x;   // 384*384
    const int k = i / DD, j = i % DD;
    At[(size_t)k * DD + j] = f2b(A[(size_t)j * DD + k]);
}

__global__ __launch_bounds__(256) void prep_bias(
    const float* __restrict__ bm1, const float* __restrict__ bv1,
    const float* __restrict__ bm2, const float* __restrict__ bv2,
    const float* __restrict__ bih, const float* __restrict__ bhh,
    float* __restrict__ bu, float* __restrict__ bmlv, float* __restrict__ br)
{
    const int i = blockIdx.x * 256 + threadIdx.x;   // 0..4095
    if (i < 1024) {
        bu[i] = i < 512 ? bm1[i] : bv1[i - 512];
    } else if (i < 1280) {
        const int j = i - 1024;
        bmlv[j] = j < 128 ? bm2[j] : bv2[j - 128];
    } else if (i >= 2048) {
        const int cb = i - 2048;
        const int gate = (cb >> 4) & 3;
        const int n = ((cb >> 6) << 4) + (cb & 15);
        const int orig = gate * 512 + n;
        br[cb] = bih[orig] + bhh[orig];
    }
}

extern "C" void kernel_launch(void* const* d_in, const int* in_sizes, int n_in,
                              void* d_out, int out_size, void* d_ws, size_t ws_size,
                              hipStream_t stream)
{
    const float* x    = (const float*)d_in[0];
    const float* A    = (const float*)d_in[3];
    const float* Wm1  = (const float*)d_in[4];
    const float* bm1  = (const float*)d_in[5];
    const float* Wm2  = (const float*)d_in[6];
    const float* bm2  = (const float*)d_in[7];
    const float* Wv1  = (const float*)d_in[8];
    const float* bv1  = (const float*)d_in[9];
    const float* Wv2  = (const float*)d_in[10];
    const float* bv2  = (const float*)d_in[11];
    const float* Wphi = (const float*)d_in[12];
    const float* bphi = (const float*)d_in[13];
    const float* W_ih = (const float*)d_in[14];
    const float* W_hh = (const float*)d_in[15];
    const float* b_ih = (const float*)d_in[16];
    const float* b_hh = (const float*)d_in[17];

    float* out = (float*)d_out;
    float* out_z    = out;
    float* out_mean = out_z + (size_t)B_ * T_ * ZD;
    float* out_lv   = out_mean + (size_t)B_ * T_ * ZD;
    float* out_hout = out_lv + (size_t)B_ * T_ * ZD;
    float* out_hlo  = out_hout + (size_t)B_ * T_ * HD;

    // ---- workspace layout (~46 MB) ----
    char* wp = (char*)d_ws;
    auto alloc_f = [&](size_t n) { float* p = (float*)wp; wp += n * sizeof(float); return p; };
    auto alloc_b = [&](size_t n) { unsigned short* p = (unsigned short*)wp; wp += n * sizeof(unsigned short); return p; };

    float* c = alloc_f((size_t)B_ * HD);
    unsigned short* hb0   = alloc_b((size_t)B_ * HD);
    unsigned short* hb1   = alloc_b((size_t)B_ * HD);
    unsigned short* xball = alloc_b((size_t)T_ * B_ * XD);
    unsigned short* umuvb = alloc_b((size_t)B_ * 1024);
    unsigned short* meanb = alloc_b((size_t)B_ * ZD);
    unsigned short* phib  = alloc_b((size_t)B_ * 1024);

    unsigned short* Wub   = alloc_b((size_t)1024 * 768);
    unsigned short* Wmlvb = alloc_b((size_t)256 * 1024);
    unsigned short* Atb   = alloc_b((size_t)DD * DD);
    unsigned short* Wphib = alloc_b((size_t)1024 * DD);
    unsigned short* Wcb   = alloc_b((size_t)1024 * DD);
    unsigned short* Wrih  = alloc_b((size_t)2048 * 1024);
    unsigned short* Wrhh  = alloc_b((size_t)2048 * 512);

    float* bu   = alloc_f(1024);
    float* bmlv = alloc_f(256);
    float* br   = alloc_f(2048);
    unsigned* bar = (unsigned*)alloc_f(64);   // barrier counter (256 B)

    const dim3 blk(256);

    // ---- prep (once per call) ----
    init_state<<<dim3(B_ * HD / 256), blk, 0, stream>>>(c, hb0, out_hout, bar);
    conv_x_all<<<dim3(B_ * T_ * XD / 4 / 256), blk, 0, stream>>>(x, xball);
    prep_wu<<<dim3(3, 1024), blk, 0, stream>>>(Wm1, Wv1, Wub);
    prep_wmlv<<<dim3(4, 256), blk, 0, stream>>>(Wm2, Wv2, Wmlvb);
    prep_wg<<<dim3(6, 2048), blk, 0, stream>>>(W_ih, W_hh, Wrih, Wrhh);
    prep_bias<<<dim3(16), blk, 0, stream>>>(bm1, bv1, bm2, bv2, b_ih, b_hh, bu, bmlv, br);
    prep_at<<<dim3(DD * DD / 256), blk, 0, stream>>>(A, Atb);
    f32_to_bf16<<<dim3(1024 * DD / 4 / 256), blk, 0, stream>>>(Wphi, Wphib, 1024 * DD / 4);
    // Wc = Wphi @ A  ([1024 x 384] bf16): folds the agg GEMM into phi
    k_gemm_plain<<<dim3(DD / 128, 1024 / 128), blk, 0, stream>>>(
        Wphib, DD, DD, Atb, DD, Wcb, DD);

    // ---- the whole 20-step recurrence: one persistent kernel ----
    k_steps<<<dim3(NBLK), blk, 0, stream>>>(
        xball, hb0, hb1, umuvb, meanb, phib,
        Wub, Wmlvb, Wcb, Wrih, Wrhh,
        bu, bmlv, br, bphi,
        c, out_z, out_mean, out_lv, out_hout, out_hlo,
        bar);
}

// Round 8
// 2343.095 us; speedup vs baseline: 3.2673x; 3.2673x over previous
//
#include <hip/hip_runtime.h>
#include <math.h>

// Problem constants
constexpr int B_ = 4096;
constexpr int T_ = 20;
constexpr int XD = 256;   // X_DIM
constexpr int ZD = 128;   // Z_DIM
constexpr int HD = 512;   // H_DIM
constexpr int DD = 384;   // X+Z

using short8 = __attribute__((ext_vector_type(8))) short;
using bf16x8 = __attribute__((ext_vector_type(8))) __bf16;
using f32x4  = __attribute__((ext_vector_type(4))) float;

__device__ __forceinline__ float lrelu_f(float v) { return v > 0.f ? v : 0.2f * v; }
__device__ __forceinline__ float softplus_f(float v) {
    return log1pf(expf(-fabsf(v))) + fmaxf(v, 0.f);
}
__device__ __forceinline__ float sigmoid_f(float v) { return 1.f / (1.f + expf(-v)); }

// float -> bf16 (round to nearest even), finite inputs
__device__ __forceinline__ unsigned short f2b(float f) {
    unsigned u = __builtin_bit_cast(unsigned, f);
    u += 0x7fff + ((u >> 16) & 1);
    return (unsigned short)(u >> 16);
}

__device__ __forceinline__ f32x4 mfma16(short8 a, short8 b, f32x4 c) {
    return __builtin_amdgcn_mfma_f32_16x16x32_bf16(
        __builtin_bit_cast(bf16x8, a), __builtin_bit_cast(bf16x8, b), c, 0, 0, 0);
}

// async global->LDS, 16 B per lane; lds base must be wave-uniform
__device__ __forceinline__ void load_lds16(const unsigned short* g, unsigned short* l) {
    __builtin_amdgcn_global_load_lds(
        (const __attribute__((address_space(1))) unsigned int*)g,
        (__attribute__((address_space(3))) unsigned int*)l,
        16, 0, 0);
}

// wait until at most `rem` K-tiles (LPT loads each) remain outstanding
template <int LPT>
__device__ __forceinline__ void vmwait(int rem) {
    if (rem >= 2) {
        if constexpr (LPT == 4) asm volatile("s_waitcnt vmcnt(8)" ::: "memory");
        else                    asm volatile("s_waitcnt vmcnt(6)" ::: "memory");
    } else if (rem == 1) {
        if constexpr (LPT == 4) asm volatile("s_waitcnt vmcnt(4)" ::: "memory");
        else                    asm volatile("s_waitcnt vmcnt(3)" ::: "memory");
    } else {
        asm volatile("s_waitcnt vmcnt(0)" ::: "memory");
    }
}

// ---------------------------------------------------------------------------
// MTx128-tile bf16 MFMA GEMM core (MT in {64,128}), 3-deep counted-vmcnt
// pipeline: tiles i (compute), i+1 (landed), i+2/i+3 (in flight).
//   C[MT,128] += A1[MT,K1] @ W1[128,K1]^T + A2[MT,K2] @ W2[128,K2]^T
// BK=32, triple-buffered LDS; per wave per K-tile LPT = MT/64+2 loads.
// Chunk swizzle c' = c ^ ((row>>1)&3) on global source AND ds_read (rule #21).
// K1,K2 multiples of 32 (K2 may be 0), K1+K2 >= 96; lda/ldw multiples of 8.
// acc[mi][ni][r]: row = bm + (wave>>1)*(MT/2) + mi*16 + (lane>>4)*4 + r,
//                 col = bn + (wave&1)*64 + ni*16 + (lane&15)
// ---------------------------------------------------------------------------
template <int MT>
__device__ __forceinline__ void gemm_core(
    const unsigned short* A1, int lda1, int K1,
    const unsigned short* A2, int lda2, int K2,
    const unsigned short* W1, int ldw1,
    const unsigned short* W2, int ldw2,
    int bm, int bn,
    unsigned short* As, unsigned short* Bs,   // As: 3*MT*32, Bs: 3*4096 shorts
    f32x4 (&acc)[MT / 32][4])
{
    constexpr int MI   = MT / 32;     // m-fragments per wave
    constexpr int WRS  = MT / 2;      // rows per wave-row-group
    constexpr int NA   = MT / 64;     // A staging rounds (1 or 2)
    constexpr int LPT  = NA + 2;      // per-wave global_load_lds per K-tile
    constexpr int ABUF = MT * 32;     // shorts per A buffer

    const int tid  = threadIdx.x;
    const int lane = tid & 63;
    const int wave = tid >> 6;
    const int wr = wave >> 1, wc = wave & 1;
    const int fr = lane & 15, fg = lane >> 4;
    const int cswz = fg ^ ((fr >> 1) & 3);      // read-side chunk swizzle

    const int r0 = tid >> 2,          c0 = (tid & 3) ^ ((r0 >> 1) & 3);
    const int r1 = (256 + tid) >> 2,  c1 = ((256 + tid) & 3) ^ ((r1 >> 1) & 3);

    const int n1 = K1 / 32;
    const int nt = n1 + K2 / 32;

    auto stage = [&](int i, int buf) {
        const unsigned short* Ag;
        const unsigned short* Wg;
        int lda, ldw, kb;
        if (i < n1) { Ag = A1; Wg = W1; lda = lda1; ldw = ldw1; kb = i * 32; }
        else        { Ag = A2; Wg = W2; lda = lda2; ldw = ldw2; kb = (i - n1) * 32; }
        unsigned short* lA = As + buf * ABUF + wave * 512;   // wave-uniform bases
        unsigned short* lB = Bs + buf * 4096 + wave * 512;
        load_lds16(Ag + (size_t)(bm + r0) * lda + kb + c0 * 8, lA);
        if constexpr (NA == 2)
            load_lds16(Ag + (size_t)(bm + r1) * lda + kb + c1 * 8, lA + 2048);
        load_lds16(Wg + (size_t)(bn + r0) * ldw + kb + c0 * 8, lB);
        load_lds16(Wg + (size_t)(bn + r1) * ldw + kb + c1 * 8, lB + 2048);
    };

    auto compute = [&](int buf) {
        const unsigned short* Ab_ = As + buf * ABUF;
        const unsigned short* Bb_ = Bs + buf * 4096;
        short8 af[MI], bv[4];
#pragma unroll
        for (int mi = 0; mi < MI; ++mi)
            af[mi] = *reinterpret_cast<const short8*>(Ab_ + (wr * WRS + mi * 16 + fr) * 32 + cswz * 8);
#pragma unroll
        for (int ni = 0; ni < 4; ++ni)
            bv[ni] = *reinterpret_cast<const short8*>(Bb_ + (wc * 64 + ni * 16 + fr) * 32 + cswz * 8);
#pragma unroll
        for (int mi = 0; mi < MI; ++mi)
#pragma unroll
            for (int ni = 0; ni < 4; ++ni)
                acc[mi][ni] = mfma16(af[mi], bv[ni], acc[mi][ni]);
    };

    // prologue: up to 3 tiles in flight
    stage(0, 0);
    if (1 < nt) stage(1, 1);
    if (2 < nt) stage(2, 2);
    {
        int rem = (nt - 1 < 2) ? (nt - 1) : 2;
        vmwait<LPT>(rem);                       // tile 0 landed
    }
    __builtin_amdgcn_s_barrier();

    int buf = 0;
    for (int i = 0; i < nt; ++i) {
        compute(buf);
        if (i + 1 < nt) {
            asm volatile("" ::: "memory");      // reads stay before barrier
            __builtin_amdgcn_s_barrier();       // all waves done reading buf
            if (i + 3 < nt) stage(i + 3, buf);  // refill freed buffer (tile (i+3)%3 == buf)
            int rem = nt - (i + 2);
            if (rem > 2) rem = 2;
            vmwait<LPT>(rem);                   // tile i+1 landed
            __builtin_amdgcn_s_barrier();
            buf = (buf == 2) ? 0 : buf + 1;
        }
    }
}

// GEMM + bias + activation -> bf16 output. ACT: 0 none, 1 lrelu, 2 softplus(lrelu)
// 1D grid decode: bn = (id & NMASK)*128, bm = (id >> NSHIFT)*MT  (weight-panel
// L2 locality: same-bn blocks land periodically on the same XCD)
template <int ACT, int MT, int NMASK, int NSHIFT>
__global__ __launch_bounds__(256) void k_gemm_act(
    const unsigned short* __restrict__ A1, int lda1, int K1,
    const unsigned short* __restrict__ A2, int lda2, int K2,
    const unsigned short* __restrict__ W1, int ldw1,
    const unsigned short* __restrict__ W2, int ldw2,
    const float* __restrict__ bias,
    unsigned short* __restrict__ DB, int lddb)
{
    __shared__ unsigned short As[3 * MT * 32];
    __shared__ unsigned short Bs[3 * 4096];
    const int id = blockIdx.x;
    const int bm = (id >> NSHIFT) * MT, bn = (id & NMASK) * 128;
    f32x4 acc[MT / 32][4] = {};
    gemm_core<MT>(A1, lda1, K1, A2, lda2, K2, W1, ldw1, W2, ldw2, bm, bn, As, Bs, acc);

    constexpr int MI = MT / 32, WRS = MT / 2;
    const int tid = threadIdx.x, lane = tid & 63, wave = tid >> 6;
    const int wr = wave >> 1, wc = wave & 1, fr = lane & 15, rg = lane >> 4;
    float bb[4];
#pragma unroll
    for (int ni = 0; ni < 4; ++ni)
        bb[ni] = bias ? bias[bn + wc * 64 + ni * 16 + fr] : 0.f;
#pragma unroll
    for (int mi = 0; mi < MI; ++mi)
#pragma unroll
        for (int r = 0; r < 4; ++r) {
            const int row = bm + wr * WRS + mi * 16 + rg * 4 + r;
#pragma unroll
            for (int ni = 0; ni < 4; ++ni) {
                float v = acc[mi][ni][r] + bb[ni];
                if (ACT == 1) v = lrelu_f(v);
                else if (ACT == 2) v = softplus_f(lrelu_f(v));
                DB[(size_t)row * lddb + (bn + wc * 64 + ni * 16 + fr)] = f2b(v);
            }
        }
}

// mean/logvar fused via block-diagonal weight [256 x 1024], MT=64:
// grid 128: bn = (id&1)*128, bm = (id>>1)*64
// cols 0-127 = mean (lrelu) -> out_z, out_mean (f32) + meanb (bf16)
// cols 128-255 = logvar (lrelu) -> out_lv (f32)
__global__ __launch_bounds__(256) void k_meanlv(
    const unsigned short* __restrict__ A,
    const unsigned short* __restrict__ W,
    const float* __restrict__ bias,
    float* __restrict__ oz, float* __restrict__ om, float* __restrict__ olv,
    unsigned short* __restrict__ meanb)
{
    __shared__ unsigned short As[3 * 64 * 32];
    __shared__ unsigned short Bs[3 * 4096];
    const int id = blockIdx.x;
    const int bm = (id >> 1) * 64, bn = (id & 1) * 128;
    f32x4 acc[2][4] = {};
    gemm_core<64>(A, 1024, 1024, A, 1024, 0, W, 1024, W, 1024, bm, bn, As, Bs, acc);

    const int tid = threadIdx.x, lane = tid & 63, wave = tid >> 6;
    const int wr = wave >> 1, wc = wave & 1, fr = lane & 15, rg = lane >> 4;
    float bb[4];
#pragma unroll
    for (int ni = 0; ni < 4; ++ni)
        bb[ni] = bias[bn + wc * 64 + ni * 16 + fr];
#pragma unroll
    for (int mi = 0; mi < 2; ++mi)
#pragma unroll
        for (int r = 0; r < 4; ++r) {
            const int row = bm + wr * 32 + mi * 16 + rg * 4 + r;
#pragma unroll
            for (int ni = 0; ni < 4; ++ni) {
                const int col = bn + wc * 64 + ni * 16 + fr;
                float v = lrelu_f(acc[mi][ni][r] + bb[ni]);
                if (bn == 0) {  // mean half
                    const size_t o = (size_t)row * (T_ * ZD) + col;
                    oz[o] = v; om[o] = v;
                    meanb[(size_t)row * ZD + col] = f2b(v);
                } else {        // logvar half
                    olv[(size_t)row * (T_ * ZD) + (col - 128)] = v;
                }
            }
        }
}

// gates GEMM (MT=128) with gate-interleaved weight rows + fused LSTM pointwise.
// 1D grid 512: bn = (id&15)*128, bm = (id>>4)*128.
// Reordered col c <-> (group=c>>6, gate=(c>>4)&3, nn=c&15), unit n=group*16+nn.
// h fp32 buffer eliminated: hn written to ohl[t] and oh[t+1].
__global__ __launch_bounds__(256) void k_gates_lstm(
    const unsigned short* __restrict__ phib,
    const unsigned short* __restrict__ hbin,
    const unsigned short* __restrict__ Wih,   // [2048][1024] reordered rows
    const unsigned short* __restrict__ Whh,   // [2048][512] reordered rows
    const float* __restrict__ br,             // reordered b_ih+b_hh
    float* __restrict__ c,
    unsigned short* __restrict__ hbout,
    float* __restrict__ ohl,                  // out_hlo + t*HD
    float* __restrict__ oh_next)              // out_hout + (t+1)*HD, or null
{
    __shared__ unsigned short As[3 * 128 * 32];
    __shared__ unsigned short Bs[3 * 4096];
    const int id = blockIdx.x;
    const int bm = (id >> 4) * 128, bn = (id & 15) * 128;
    f32x4 acc[4][4] = {};
    gemm_core<128>(phib, 1024, 1024, hbin, 512, 512, Wih, 1024, Whh, 512, bm, bn, As, Bs, acc);

    const int tid = threadIdx.x, lane = tid & 63, wave = tid >> 6;
    const int wr = wave >> 1, wc = wave & 1, fr = lane & 15, rg = lane >> 4;
    const int n = ((bn + wc * 64) >> 6) * 16 + fr;     // hidden unit index
    float bb[4];
#pragma unroll
    for (int ni = 0; ni < 4; ++ni)
        bb[ni] = br[bn + wc * 64 + ni * 16 + fr];
#pragma unroll
    for (int mi = 0; mi < 4; ++mi)
#pragma unroll
        for (int r = 0; r < 4; ++r) {
            const int row = bm + wr * 64 + mi * 16 + rg * 4 + r;
            const size_t idx = (size_t)row * HD + n;
            const float gi = acc[mi][0][r] + bb[0];
            const float gf = acc[mi][1][r] + bb[1];
            const float gg = acc[mi][2][r] + bb[2];
            const float go = acc[mi][3][r] + bb[3];
            const float co = c[idx];
            const float cn = sigmoid_f(gf) * co + sigmoid_f(gi) * tanhf(gg);
            const float hn = sigmoid_f(go) * tanhf(cn);
            c[idx] = cn;
            hbout[idx] = f2b(hn);
            const size_t ob = (size_t)row * (T_ * HD) + n;
            ohl[ob] = hn;                       // h after update
            if (oh_next) oh_next[ob] = hn;      // == h BEFORE update at t+1
        }
}

// ---------------------------------------------------------------------------
// prep GEMM (MT=128 core, 2D grid) for Wc = Wphi @ A
__global__ __launch_bounds__(256) void k_gemm_plain(
    const unsigned short* __restrict__ A1, int lda1, int K1,
    const unsigned short* __restrict__ W1, int ldw1,
    unsigned short* __restrict__ DB, int lddb)
{
    __shared__ unsigned short As[3 * 128 * 32];
    __shared__ unsigned short Bs[3 * 4096];
    const int bm = blockIdx.y * 128, bn = blockIdx.x * 128;
    f32x4 acc[4][4] = {};
    gemm_core<128>(A1, lda1, K1, A1, lda1, 0, W1, ldw1, W1, ldw1, bm, bn, As, Bs, acc);

    const int tid = threadIdx.x, lane = tid & 63, wave = tid >> 6;
    const int wr = wave >> 1, wc = wave & 1, fr = lane & 15, rg = lane >> 4;
#pragma unroll
    for (int mi = 0; mi < 4; ++mi)
#pragma unroll
        for (int r = 0; r < 4; ++r) {
            const int row = bm + wr * 64 + mi * 16 + rg * 4 + r;
#pragma unroll
            for (int ni = 0; ni < 4; ++ni) {
                const int col = bn + wc * 64 + ni * 16 + fr;
                DB[(size_t)row * lddb + col] = f2b(acc[mi][ni][r]);
            }
        }
}

// init: c = 0, hb0 = 0, out_hout[:, 0, :] = 0 (d_out is poisoned by harness)
__global__ __launch_bounds__(256) void init_state(
    float* __restrict__ c, unsigned short* __restrict__ hb,
    float* __restrict__ oh0)
{
    const int i = blockIdx.x * 256 + threadIdx.x;   // B_*HD
    c[i] = 0.f; hb[i] = 0;
    const int b = i >> 9, nn = i & 511;
    oh0[(size_t)b * (T_ * HD) + nn] = 0.f;
}

__global__ __launch_bounds__(256) void f32_to_bf16(
    const float* __restrict__ src, unsigned short* __restrict__ dst, int n4)
{
    const int i = blockIdx.x * 256 + threadIdx.x;
    if (i >= n4) return;
    float4 v = reinterpret_cast<const float4*>(src)[i];
    ushort4 o;
    o.x = f2b(v.x); o.y = f2b(v.y); o.z = f2b(v.z); o.w = f2b(v.w);
    reinterpret_cast<ushort4*>(dst)[i] = o;
}

// all x slices: x [B][T][XD] fp32 -> xball [T][B][XD] bf16 (row = t*B+b)
__global__ __launch_bounds__(256) void conv_x_all(
    const float* __restrict__ x, unsigned short* __restrict__ xball)
{
    const int i = blockIdx.x * 256 + threadIdx.x;   // < B_*T_*XD/4
    const int d = i & 63;                           // float4 within row
    const int bt = i >> 6;
    const int b = bt / T_, t = bt % T_;
    float4 v = reinterpret_cast<const float4*>(x)[i];
    ushort4 o;
    o.x = f2b(v.x); o.y = f2b(v.y); o.z = f2b(v.z); o.w = f2b(v.w);
    reinterpret_cast<ushort4*>(xball)[((size_t)t * B_ + b) * (XD / 4) + d] = o;
}

// Wub[1024][768] = [Wm1; Wv1] (bf16)
__global__ __launch_bounds__(256) void prep_wu(
    const float* __restrict__ Wm1, const float* __restrict__ Wv1,
    unsigned short* __restrict__ Wub)
{
    const int k = blockIdx.x * 256 + threadIdx.x;   // 0..767
    const int nrow = blockIdx.y;                    // 0..1023
    const float v = nrow < 512 ? Wm1[nrow * 768 + k] : Wv1[(nrow - 512) * 768 + k];
    Wub[nrow * 768 + k] = f2b(v);
}

// Wmlv[256][1024] block-diagonal: [Wm2 0; 0 Wv2] (bf16)
__global__ __launch_bounds__(256) void prep_wmlv(
    const float* __restrict__ Wm2, const float* __restrict__ Wv2,
    unsigned short* __restrict__ Wmlv)
{
    const int k = blockIdx.x * 256 + threadIdx.x;   // 0..1023
    const int cc = blockIdx.y;                      // 0..255
    float v = 0.f;
    if (cc < 128) { if (k < 512) v = Wm2[cc * 512 + k]; }
    else          { if (k >= 512) v = Wv2[(cc - 128) * 512 + (k - 512)]; }
    Wmlv[cc * 1024 + k] = f2b(v);
}

// gate-interleaved reorder of W_ih, W_hh
__global__ __launch_bounds__(256) void prep_wg(
    const float* __restrict__ Wih, const float* __restrict__ Whh,
    unsigned short* __restrict__ Wrih, unsigned short* __restrict__ Wrhh)
{
    const int cc = blockIdx.y;                      // 0..2047
    const int gate = (cc >> 4) & 3;
    const int n = ((cc >> 6) << 4) + (cc & 15);
    const int orig = gate * 512 + n;
    const int kk = blockIdx.x * 256 + threadIdx.x;  // 0..1535
    if (kk < 1024) Wrih[(size_t)cc * 1024 + kk] = f2b(Wih[(size_t)orig * 1024 + kk]);
    else           Wrhh[(size_t)cc * 512 + (kk - 1024)] = f2b(Whh[(size_t)orig * 512 + (kk - 1024)]);
}

// At[k][j] = bf16(A[j][k])  (A is [384][384] fp32 row-major)
__global__ __launch_bounds__(256) void prep_at(
    const float* __restrict__ A, unsigned short* __restrict__ At)
{
    const int i = blockIdx.x * 256 + threadIdx.x;   // 384*384
    const int k = i / DD, j = i % DD;
    At[(size_t)k * DD + j] = f2b(A[(size_t)j * DD + k]);
}

__global__ __launch_bounds__(256) void prep_bias(
    const float* __restrict__ bm1, const float* __restrict__ bv1,
    const float* __restrict__ bm2, const float* __restrict__ bv2,
    const float* __restrict__ bih, const float* __restrict__ bhh,
    float* __restrict__ bu, float* __restrict__ bmlv, float* __restrict__ br)
{
    const int i = blockIdx.x * 256 + threadIdx.x;   // 0..4095
    if (i < 1024) {
        bu[i] = i < 512 ? bm1[i] : bv1[i - 512];
    } else if (i < 1280) {
        const int j = i - 1024;
        bmlv[j] = j < 128 ? bm2[j] : bv2[j - 128];
    } else if (i >= 2048) {
        const int cb = i - 2048;
        const int gate = (cb >> 4) & 3;
        const int n = ((cb >> 6) << 4) + (cb & 15);
        const int orig = gate * 512 + n;
        br[cb] = bih[orig] + bhh[orig];
    }
}

extern "C" void kernel_launch(void* const* d_in, const int* in_sizes, int n_in,
                              void* d_out, int out_size, void* d_ws, size_t ws_size,
                              hipStream_t stream)
{
    const float* x    = (const float*)d_in[0];
    const float* A    = (const float*)d_in[3];
    const float* Wm1  = (const float*)d_in[4];
    const float* bm1  = (const float*)d_in[5];
    const float* Wm2  = (const float*)d_in[6];
    const float* bm2  = (const float*)d_in[7];
    const float* Wv1  = (const float*)d_in[8];
    const float* bv1  = (const float*)d_in[9];
    const float* Wv2  = (const float*)d_in[10];
    const float* bv2  = (const float*)d_in[11];
    const float* Wphi = (const float*)d_in[12];
    const float* bphi = (const float*)d_in[13];
    const float* W_ih = (const float*)d_in[14];
    const float* W_hh = (const float*)d_in[15];
    const float* b_ih = (const float*)d_in[16];
    const float* b_hh = (const float*)d_in[17];

    float* out = (float*)d_out;
    float* out_z    = out;
    float* out_mean = out_z + (size_t)B_ * T_ * ZD;
    float* out_lv   = out_mean + (size_t)B_ * T_ * ZD;
    float* out_hout = out_lv + (size_t)B_ * T_ * ZD;
    float* out_hlo  = out_hout + (size_t)B_ * T_ * HD;

    // ---- workspace layout (~46 MB) ----
    char* wp = (char*)d_ws;
    auto alloc_f = [&](size_t n) { float* p = (float*)wp; wp += n * sizeof(float); return p; };
    auto alloc_b = [&](size_t n) { unsigned short* p = (unsigned short*)wp; wp += n * sizeof(unsigned short); return p; };

    float* c = alloc_f((size_t)B_ * HD);
    unsigned short* hb0   = alloc_b((size_t)B_ * HD);
    unsigned short* hb1   = alloc_b((size_t)B_ * HD);
    unsigned short* xball = alloc_b((size_t)T_ * B_ * XD);
    unsigned short* umuvb = alloc_b((size_t)B_ * 1024);
    unsigned short* meanb = alloc_b((size_t)B_ * ZD);
    unsigned short* phib  = alloc_b((size_t)B_ * 1024);

    unsigned short* Wub   = alloc_b((size_t)1024 * 768);
    unsigned short* Wmlvb = alloc_b((size_t)256 * 1024);
    unsigned short* Atb   = alloc_b((size_t)DD * DD);
    unsigned short* Wphib = alloc_b((size_t)1024 * DD);
    unsigned short* Wcb   = alloc_b((size_t)1024 * DD);
    unsigned short* Wrih  = alloc_b((size_t)2048 * 1024);
    unsigned short* Wrhh  = alloc_b((size_t)2048 * 512);

    float* bu   = alloc_f(1024);
    float* bmlv = alloc_f(256);
    float* br   = alloc_f(2048);

    const dim3 blk(256);

    // ---- prep (once per call) ----
    init_state<<<dim3(B_ * HD / 256), blk, 0, stream>>>(c, hb0, out_hout);
    conv_x_all<<<dim3(B_ * T_ * XD / 4 / 256), blk, 0, stream>>>(x, xball);
    prep_wu<<<dim3(3, 1024), blk, 0, stream>>>(Wm1, Wv1, Wub);
    prep_wmlv<<<dim3(4, 256), blk, 0, stream>>>(Wm2, Wv2, Wmlvb);
    prep_wg<<<dim3(6, 2048), blk, 0, stream>>>(W_ih, W_hh, Wrih, Wrhh);
    prep_bias<<<dim3(16), blk, 0, stream>>>(bm1, bv1, bm2, bv2, b_ih, b_hh, bu, bmlv, br);
    prep_at<<<dim3(DD * DD / 256), blk, 0, stream>>>(A, Atb);
    f32_to_bf16<<<dim3(1024 * DD / 4 / 256), blk, 0, stream>>>(Wphi, Wphib, 1024 * DD / 4);
    // Wc = Wphi @ A  ([1024 x 384] bf16): folds the agg GEMM into phi
    k_gemm_plain<<<dim3(DD / 128, 1024 / 128), blk, 0, stream>>>(
        Wphib, DD, DD, Atb, DD, Wcb, DD);

    for (int t = 0; t < T_; ++t) {
        unsigned short* hbt = (t & 1) ? hb1 : hb0;   // h_t  (read)
        unsigned short* hbn = (t & 1) ? hb0 : hb1;   // h_{t+1} (written by epilogue)
        const unsigned short* xb = xball + (size_t)t * B_ * XD;

        // [u_m | u_v] = lrelu([x_t, h] @ Wub^T + bu)   [B, 1024]  MT=64, grid 512
        k_gemm_act<1, 64, 7, 3><<<dim3(512), blk, 0, stream>>>(
            xb, XD, XD, hbt, HD, HD,
            Wub, XD + HD, Wub + XD, XD + HD,
            bu, umuvb, 1024);

        // mean -> out_z/out_mean/meanb ; logvar -> out_lv   MT=64, grid 128
        k_meanlv<<<dim3(128), blk, 0, stream>>>(
            umuvb, Wmlvb, bmlv,
            out_z + (size_t)t * ZD, out_mean + (size_t)t * ZD,
            out_lv + (size_t)t * ZD, meanb);

        // phi = softplus(lrelu([x_t, mean] @ Wc^T + bphi))   [B, 1024]  MT=64, grid 512
        k_gemm_act<2, 64, 7, 3><<<dim3(512), blk, 0, stream>>>(
            xb, XD, XD, meanb, ZD, ZD,
            Wcb, DD, Wcb + XD, DD,
            bphi, phib, 1024);

        // gates (reordered) + fused LSTM   MT=128, grid 512
        k_gates_lstm<<<dim3(512), blk, 0, stream>>>(
            phib, hbt, Wrih, Wrhh, br,
            c, hbn,
            out_hlo + (size_t)t * HD,
            (t + 1 < T_) ? out_hout + (size_t)(t + 1) * HD : nullptr);
    }
}

// Round 9
// 2064.901 us; speedup vs baseline: 3.7075x; 1.1347x over previous
//
#include <hip/hip_runtime.h>
#include <math.h>

// Problem constants
constexpr int B_ = 4096;
constexpr int T_ = 20;
constexpr int XD = 256;   // X_DIM
constexpr int ZD = 128;   // Z_DIM
constexpr int HD = 512;   // H_DIM
constexpr int DD = 384;   // X+Z

using short8 = __attribute__((ext_vector_type(8))) short;
using bf16x8 = __attribute__((ext_vector_type(8))) __bf16;
using f32x4  = __attribute__((ext_vector_type(4))) float;

__device__ __forceinline__ float lrelu_f(float v) { return v > 0.f ? v : 0.2f * v; }
__device__ __forceinline__ float softplus_f(float v) {
    return log1pf(expf(-fabsf(v))) + fmaxf(v, 0.f);
}
__device__ __forceinline__ float sigmoid_f(float v) { return 1.f / (1.f + expf(-v)); }

// float -> bf16 (round to nearest even), finite inputs
__device__ __forceinline__ unsigned short f2b(float f) {
    unsigned u = __builtin_bit_cast(unsigned, f);
    u += 0x7fff + ((u >> 16) & 1);
    return (unsigned short)(u >> 16);
}

__device__ __forceinline__ f32x4 mfma16(short8 a, short8 b, f32x4 c) {
    return __builtin_amdgcn_mfma_f32_16x16x32_bf16(
        __builtin_bit_cast(bf16x8, a), __builtin_bit_cast(bf16x8, b), c, 0, 0, 0);
}

// async global->LDS, 16 B per lane; lds base must be wave-uniform
__device__ __forceinline__ void load_lds16(const unsigned short* g, unsigned short* l) {
    __builtin_amdgcn_global_load_lds(
        (const __attribute__((address_space(1))) unsigned int*)g,
        (__attribute__((address_space(3))) unsigned int*)l,
        16, 0, 0);
}

// wait until at most `rem` K-tiles (LPT loads each) remain outstanding
template <int LPT>
__device__ __forceinline__ void vmwait(int rem) {
    if (rem >= 2) {
        if constexpr (LPT == 4)      asm volatile("s_waitcnt vmcnt(8)" ::: "memory");
        else if constexpr (LPT == 3) asm volatile("s_waitcnt vmcnt(6)" ::: "memory");
        else                         asm volatile("s_waitcnt vmcnt(4)" ::: "memory");
    } else if (rem == 1) {
        if constexpr (LPT == 4)      asm volatile("s_waitcnt vmcnt(4)" ::: "memory");
        else if constexpr (LPT == 3) asm volatile("s_waitcnt vmcnt(3)" ::: "memory");
        else                         asm volatile("s_waitcnt vmcnt(2)" ::: "memory");
    } else {
        asm volatile("s_waitcnt vmcnt(0)" ::: "memory");
    }
}

// ---------------------------------------------------------------------------
// MTx128-tile bf16 MFMA GEMM core (MT in {64,128}), 3-deep counted-vmcnt
// pipeline: tiles i (compute), i+1 (landed), i+2/i+3 (in flight).
//   C[MT,128] += A1[MT,K1] @ W1[128,K1]^T + A2[MT,K2] @ W2[128,K2]^T
// BK=32, triple-buffered LDS; per wave per K-tile LPT = MT/64+2 loads.
// Chunk swizzle c' = c ^ ((row>>1)&3) on global source AND ds_read (rule #21).
// K1,K2 multiples of 32 (K2 may be 0), K1+K2 >= 96; lda/ldw multiples of 8.
// acc[mi][ni][r]: row = bm + (wave>>1)*(MT/2) + mi*16 + (lane>>4)*4 + r,
//                 col = bn + (wave&1)*64 + ni*16 + (lane&15)
// ---------------------------------------------------------------------------
template <int MT>
__device__ __forceinline__ void gemm_core(
    const unsigned short* A1, int lda1, int K1,
    const unsigned short* A2, int lda2, int K2,
    const unsigned short* W1, int ldw1,
    const unsigned short* W2, int ldw2,
    int bm, int bn,
    unsigned short* As, unsigned short* Bs,   // As: 3*MT*32, Bs: 3*4096 shorts
    f32x4 (&acc)[MT / 32][4])
{
    constexpr int MI   = MT / 32;     // m-fragments per wave
    constexpr int WRS  = MT / 2;      // rows per wave-row-group
    constexpr int NA   = MT / 64;     // A staging rounds (1 or 2)
    constexpr int LPT  = NA + 2;      // per-wave global_load_lds per K-tile
    constexpr int ABUF = MT * 32;     // shorts per A buffer

    const int tid  = threadIdx.x;
    const int lane = tid & 63;
    const int wave = tid >> 6;
    const int wr = wave >> 1, wc = wave & 1;
    const int fr = lane & 15, fg = lane >> 4;
    const int cswz = fg ^ ((fr >> 1) & 3);      // read-side chunk swizzle

    const int r0 = tid >> 2,          c0 = (tid & 3) ^ ((r0 >> 1) & 3);
    const int r1 = (256 + tid) >> 2,  c1 = ((256 + tid) & 3) ^ ((r1 >> 1) & 3);

    const int n1 = K1 / 32;
    const int nt = n1 + K2 / 32;

    auto stage = [&](int i, int buf) {
        const unsigned short* Ag;
        const unsigned short* Wg;
        int lda, ldw, kb;
        if (i < n1) { Ag = A1; Wg = W1; lda = lda1; ldw = ldw1; kb = i * 32; }
        else        { Ag = A2; Wg = W2; lda = lda2; ldw = ldw2; kb = (i - n1) * 32; }
        unsigned short* lA = As + buf * ABUF + wave * 512;   // wave-uniform bases
        unsigned short* lB = Bs + buf * 4096 + wave * 512;
        load_lds16(Ag + (size_t)(bm + r0) * lda + kb + c0 * 8, lA);
        if constexpr (NA == 2)
            load_lds16(Ag + (size_t)(bm + r1) * lda + kb + c1 * 8, lA + 2048);
        load_lds16(Wg + (size_t)(bn + r0) * ldw + kb + c0 * 8, lB);
        load_lds16(Wg + (size_t)(bn + r1) * ldw + kb + c1 * 8, lB + 2048);
    };

    auto compute = [&](int buf) {
        const unsigned short* Ab_ = As + buf * ABUF;
        const unsigned short* Bb_ = Bs + buf * 4096;
        short8 af[MI], bv[4];
#pragma unroll
        for (int mi = 0; mi < MI; ++mi)
            af[mi] = *reinterpret_cast<const short8*>(Ab_ + (wr * WRS + mi * 16 + fr) * 32 + cswz * 8);
#pragma unroll
        for (int ni = 0; ni < 4; ++ni)
            bv[ni] = *reinterpret_cast<const short8*>(Bb_ + (wc * 64 + ni * 16 + fr) * 32 + cswz * 8);
#pragma unroll
        for (int mi = 0; mi < MI; ++mi)
#pragma unroll
            for (int ni = 0; ni < 4; ++ni)
                acc[mi][ni] = mfma16(af[mi], bv[ni], acc[mi][ni]);
    };

    // prologue: up to 3 tiles in flight
    stage(0, 0);
    if (1 < nt) stage(1, 1);
    if (2 < nt) stage(2, 2);
    {
        int rem = (nt - 1 < 2) ? (nt - 1) : 2;
        vmwait<LPT>(rem);                       // tile 0 landed
    }
    __builtin_amdgcn_s_barrier();

    int buf = 0;
    for (int i = 0; i < nt; ++i) {
        compute(buf);
        if (i + 1 < nt) {
            asm volatile("" ::: "memory");      // reads stay before barrier
            __builtin_amdgcn_s_barrier();       // all waves done reading buf
            if (i + 3 < nt) stage(i + 3, buf);  // refill freed buffer
            int rem = nt - (i + 2);
            if (rem > 2) rem = 2;
            vmwait<LPT>(rem);                   // tile i+1 landed
            __builtin_amdgcn_s_barrier();
            buf = (buf == 2) ? 0 : buf + 1;
        }
    }
}

// GEMM + bias + activation -> bf16 output. ACT: 0 none, 1 lrelu, 2 softplus(lrelu)
// 1D grid decode: bn = (id & NMASK)*128, bm = (id >> NSHIFT)*MT
template <int ACT, int MT, int NMASK, int NSHIFT>
__global__ __launch_bounds__(256) void k_gemm_act(
    const unsigned short* __restrict__ A1, int lda1, int K1,
    const unsigned short* __restrict__ A2, int lda2, int K2,
    const unsigned short* __restrict__ W1, int ldw1,
    const unsigned short* __restrict__ W2, int ldw2,
    const float* __restrict__ bias,
    unsigned short* __restrict__ DB, int lddb)
{
    __shared__ unsigned short As[3 * MT * 32];
    __shared__ unsigned short Bs[3 * 4096];
    const int id = blockIdx.x;
    const int bm = (id >> NSHIFT) * MT, bn = (id & NMASK) * 128;
    f32x4 acc[MT / 32][4] = {};
    gemm_core<MT>(A1, lda1, K1, A2, lda2, K2, W1, ldw1, W2, ldw2, bm, bn, As, Bs, acc);

    constexpr int MI = MT / 32, WRS = MT / 2;
    const int tid = threadIdx.x, lane = tid & 63, wave = tid >> 6;
    const int wr = wave >> 1, wc = wave & 1, fr = lane & 15, rg = lane >> 4;
    float bb[4];
#pragma unroll
    for (int ni = 0; ni < 4; ++ni)
        bb[ni] = bias ? bias[bn + wc * 64 + ni * 16 + fr] : 0.f;
#pragma unroll
    for (int mi = 0; mi < MI; ++mi)
#pragma unroll
        for (int r = 0; r < 4; ++r) {
            const int row = bm + wr * WRS + mi * 16 + rg * 4 + r;
#pragma unroll
            for (int ni = 0; ni < 4; ++ni) {
                float v = acc[mi][ni][r] + bb[ni];
                if (ACT == 1) v = lrelu_f(v);
                else if (ACT == 2) v = softplus_f(lrelu_f(v));
                DB[(size_t)row * lddb + (bn + wc * 64 + ni * 16 + fr)] = f2b(v);
            }
        }
}

// ---------------------------------------------------------------------------
// Fused mean + phi kernel (replaces k_meanlv + phi GEMM):
// grid 512: bm = (id>>3)*64 rows, bn = (id&7)*128 phi-cols.
// Stage 1: mean = lrelu(u_m @ Wm2^T + bm2) for this block's 64 rows (all 128
//          cols), kept in padded LDS meanL[64][136]; bn==0 writes out_z/out_mean.
// Stage 2: phi x-part (K=256) via gemm_core.
// Stage 3: phi mean-part (K=128, 4 tiles): A-fragments straight from meanL,
//          B streamed with the same swizzled staging. Same K-tile order as the
//          previous split kernels -> bit-identical results.
// ---------------------------------------------------------------------------
__global__ __launch_bounds__(256) void k_meanphi(
    const unsigned short* __restrict__ uslot,  // umuvall + t*B*1024, [B][1024]
    const unsigned short* __restrict__ xb,     // [B][256]
    const unsigned short* __restrict__ Wm2b,   // [128][512]
    const unsigned short* __restrict__ Wcb,    // [1024][384]
    const float* __restrict__ bm2,             // [128]
    const float* __restrict__ bphi,            // [1024]
    float* __restrict__ oz, float* __restrict__ om,   // + t*ZD, stride T*ZD
    unsigned short* __restrict__ phib)
{
    __shared__ unsigned short As[3 * 64 * 32];
    __shared__ unsigned short Bs[3 * 4096];
    __shared__ unsigned short meanL[64 * 136];   // pad 136: conflict-light

    const int id = blockIdx.x;
    const int bm = (id >> 3) * 64, bn = (id & 7) * 128;
    const int tid = threadIdx.x, lane = tid & 63, wave = tid >> 6;
    const int wr = wave >> 1, wc = wave & 1, fr = lane & 15, fg = lane >> 4, rg = lane >> 4;
    const int cswz = fg ^ ((fr >> 1) & 3);
    const int r0 = tid >> 2,          c0 = (tid & 3) ^ ((r0 >> 1) & 3);
    const int r1 = (256 + tid) >> 2,  c1 = ((256 + tid) & 3) ^ ((r1 >> 1) & 3);

    // ---- stage 1: mean (N=128 -> bn arg 0) ----
    {
        f32x4 macc[2][4] = {};
        gemm_core<64>(uslot, 1024, 512, uslot, 1024, 0,
                      Wm2b, 512, Wm2b, 512, bm, 0, As, Bs, macc);
        float mb[4];
#pragma unroll
        for (int ni = 0; ni < 4; ++ni)
            mb[ni] = bm2[wc * 64 + ni * 16 + fr];
#pragma unroll
        for (int mi = 0; mi < 2; ++mi)
#pragma unroll
            for (int r = 0; r < 4; ++r) {
                const int rowl = wr * 32 + mi * 16 + rg * 4 + r;
#pragma unroll
                for (int ni = 0; ni < 4; ++ni) {
                    const int col = wc * 64 + ni * 16 + fr;
                    const float v = lrelu_f(macc[mi][ni][r] + mb[ni]);
                    meanL[rowl * 136 + col] = f2b(v);
                    if (bn == 0) {
                        const size_t o = (size_t)(bm + rowl) * (T_ * ZD) + col;
                        oz[o] = v; om[o] = v;
                    }
                }
            }
    }
    __syncthreads();   // meanL complete; all waves past stage-1 LDS reads

    // ---- stage 2: phi x-part (K=256) ----
    f32x4 acc[2][4] = {};
    gemm_core<64>(xb, XD, XD, xb, XD, 0,
                  Wcb, DD, Wcb, DD, bm, bn, As, Bs, acc);
    __syncthreads();   // all waves done with stage-2 LDS before restaging

    // ---- stage 3: phi mean-part (K=128, 4 tiles), A from meanL ----
    {
        const unsigned short* WG = Wcb + XD;   // mean-columns of Wc
        auto stageB = [&](int i, int buf) {
            unsigned short* lB = Bs + buf * 4096 + wave * 512;
            load_lds16(WG + (size_t)(bn + r0) * DD + i * 32 + c0 * 8, lB);
            load_lds16(WG + (size_t)(bn + r1) * DD + i * 32 + c1 * 8, lB + 2048);
        };
        stageB(0, 0); stageB(1, 1); stageB(2, 2);
        vmwait<2>(2);
        __builtin_amdgcn_s_barrier();
        int buf = 0;
        for (int i = 0; i < 4; ++i) {
            short8 af[2], bv[4];
#pragma unroll
            for (int mi = 0; mi < 2; ++mi)
                af[mi] = *reinterpret_cast<const short8*>(
                    meanL + (wr * 32 + mi * 16 + fr) * 136 + i * 32 + fg * 8);
#pragma unroll
            for (int ni = 0; ni < 4; ++ni)
                bv[ni] = *reinterpret_cast<const short8*>(
                    Bs + buf * 4096 + (wc * 64 + ni * 16 + fr) * 32 + cswz * 8);
#pragma unroll
            for (int mi = 0; mi < 2; ++mi)
#pragma unroll
                for (int ni = 0; ni < 4; ++ni)
                    acc[mi][ni] = mfma16(af[mi], bv[ni], acc[mi][ni]);
            if (i + 1 < 4) {
                asm volatile("" ::: "memory");
                __builtin_amdgcn_s_barrier();
                if (i + 3 < 4) stageB(i + 3, buf);
                int rem = 4 - (i + 2);
                if (rem > 2) rem = 2;
                vmwait<2>(rem);
                __builtin_amdgcn_s_barrier();
                buf = (buf == 2) ? 0 : buf + 1;
            }
        }
    }

    // ---- epilogue: softplus(lrelu(.)) -> phib ----
    float pb[4];
#pragma unroll
    for (int ni = 0; ni < 4; ++ni)
        pb[ni] = bphi[bn + wc * 64 + ni * 16 + fr];
#pragma unroll
    for (int mi = 0; mi < 2; ++mi)
#pragma unroll
        for (int r = 0; r < 4; ++r) {
            const int row = bm + wr * 32 + mi * 16 + rg * 4 + r;
#pragma unroll
            for (int ni = 0; ni < 4; ++ni) {
                const float v = softplus_f(lrelu_f(acc[mi][ni][r] + pb[ni]));
                phib[(size_t)row * 1024 + (bn + wc * 64 + ni * 16 + fr)] = f2b(v);
            }
        }
}

// ---------------------------------------------------------------------------
// Batched logvar over ALL steps: A = umuvall[:, 512:1024] as [T*B][1024],
// W = Wv2b [128][512]. Grid 1280 (MT=64, N=128). Off the recurrence path.
__global__ __launch_bounds__(256) void k_logvar_all(
    const unsigned short* __restrict__ umuvall,
    const unsigned short* __restrict__ Wv2b,
    const float* __restrict__ bv2,
    float* __restrict__ out_lv)               // [B][T][ZD]
{
    __shared__ unsigned short As[3 * 64 * 32];
    __shared__ unsigned short Bs[3 * 4096];
    const int bm = blockIdx.x * 64;
    f32x4 acc[2][4] = {};
    gemm_core<64>(umuvall + 512, 1024, 512, umuvall + 512, 1024, 0,
                  Wv2b, 512, Wv2b, 512, bm, 0, As, Bs, acc);

    const int tid = threadIdx.x, lane = tid & 63, wave = tid >> 6;
    const int wr = wave >> 1, wc = wave & 1, fr = lane & 15, rg = lane >> 4;
    float bb[4];
#pragma unroll
    for (int ni = 0; ni < 4; ++ni)
        bb[ni] = bv2[wc * 64 + ni * 16 + fr];
#pragma unroll
    for (int mi = 0; mi < 2; ++mi)
#pragma unroll
        for (int r = 0; r < 4; ++r) {
            const int row = bm + wr * 32 + mi * 16 + rg * 4 + r;   // t*B + b
            const int t = row >> 12, b = row & (B_ - 1);
#pragma unroll
            for (int ni = 0; ni < 4; ++ni) {
                const int col = wc * 64 + ni * 16 + fr;
                out_lv[(size_t)b * (T_ * ZD) + (size_t)t * ZD + col] =
                    lrelu_f(acc[mi][ni][r] + bb[ni]);
            }
        }
}

// gates GEMM (MT=128) with gate-interleaved weight rows + fused LSTM pointwise.
// XCD-chunked swizzle (T1): sid=(id&7)*64+(id>>3); bn=(sid&15)*128, bm=(sid>>4)*128
// -> each XCD works 4 consecutive bm-panels (A-set 1.5 MB fits its L2).
__global__ __launch_bounds__(256) void k_gates_lstm(
    const unsigned short* __restrict__ phib,
    const unsigned short* __restrict__ hbin,
    const unsigned short* __restrict__ Wih,   // [2048][1024] reordered rows
    const unsigned short* __restrict__ Whh,   // [2048][512] reordered rows
    const float* __restrict__ br,             // reordered b_ih+b_hh
    float* __restrict__ c,
    unsigned short* __restrict__ hbout,
    float* __restrict__ ohl,                  // out_hlo + t*HD
    float* __restrict__ oh_next)              // out_hout + (t+1)*HD, or null
{
    __shared__ unsigned short As[3 * 128 * 32];
    __shared__ unsigned short Bs[3 * 4096];
    const int id = blockIdx.x;
    const int sid = (id & 7) * 64 + (id >> 3);         // bijective for 512
    const int bm = (sid >> 4) * 128, bn = (sid & 15) * 128;
    f32x4 acc[4][4] = {};
    gemm_core<128>(phib, 1024, 1024, hbin, 512, 512, Wih, 1024, Whh, 512, bm, bn, As, Bs, acc);

    const int tid = threadIdx.x, lane = tid & 63, wave = tid >> 6;
    const int wr = wave >> 1, wc = wave & 1, fr = lane & 15, rg = lane >> 4;
    const int n = ((bn + wc * 64) >> 6) * 16 + fr;     // hidden unit index
    float bb[4];
#pragma unroll
    for (int ni = 0; ni < 4; ++ni)
        bb[ni] = br[bn + wc * 64 + ni * 16 + fr];
#pragma unroll
    for (int mi = 0; mi < 4; ++mi)
#pragma unroll
        for (int r = 0; r < 4; ++r) {
            const int row = bm + wr * 64 + mi * 16 + rg * 4 + r;
            const size_t idx = (size_t)row * HD + n;
            const float gi = acc[mi][0][r] + bb[0];
            const float gf = acc[mi][1][r] + bb[1];
            const float gg = acc[mi][2][r] + bb[2];
            const float go = acc[mi][3][r] + bb[3];
            const float co = c[idx];
            const float cn = sigmoid_f(gf) * co + sigmoid_f(gi) * tanhf(gg);
            const float hn = sigmoid_f(go) * tanhf(cn);
            c[idx] = cn;
            hbout[idx] = f2b(hn);
            const size_t ob = (size_t)row * (T_ * HD) + n;
            ohl[ob] = hn;                       // h after update
            if (oh_next) oh_next[ob] = hn;      // == h BEFORE update at t+1
        }
}

// ---------------------------------------------------------------------------
// prep GEMM (MT=128 core, 2D grid) for Wc = Wphi @ A
__global__ __launch_bounds__(256) void k_gemm_plain(
    const unsigned short* __restrict__ A1, int lda1, int K1,
    const unsigned short* __restrict__ W1, int ldw1,
    unsigned short* __restrict__ DB, int lddb)
{
    __shared__ unsigned short As[3 * 128 * 32];
    __shared__ unsigned short Bs[3 * 4096];
    const int bm = blockIdx.y * 128, bn = blockIdx.x * 128;
    f32x4 acc[4][4] = {};
    gemm_core<128>(A1, lda1, K1, A1, lda1, 0, W1, ldw1, W1, ldw1, bm, bn, As, Bs, acc);

    const int tid = threadIdx.x, lane = tid & 63, wave = tid >> 6;
    const int wr = wave >> 1, wc = wave & 1, fr = lane & 15, rg = lane >> 4;
#pragma unroll
    for (int mi = 0; mi < 4; ++mi)
#pragma unroll
        for (int r = 0; r < 4; ++r) {
            const int row = bm + wr * 64 + mi * 16 + rg * 4 + r;
#pragma unroll
            for (int ni = 0; ni < 4; ++ni) {
                const int col = bn + wc * 64 + ni * 16 + fr;
                DB[(size_t)row * lddb + col] = f2b(acc[mi][ni][r]);
            }
        }
}

// init: c = 0, hb0 = 0, out_hout[:, 0, :] = 0 (d_out is poisoned by harness)
__global__ __launch_bounds__(256) void init_state(
    float* __restrict__ c, unsigned short* __restrict__ hb,
    float* __restrict__ oh0)
{
    const int i = blockIdx.x * 256 + threadIdx.x;   // B_*HD
    c[i] = 0.f; hb[i] = 0;
    const int b = i >> 9, nn = i & 511;
    oh0[(size_t)b * (T_ * HD) + nn] = 0.f;
}

__global__ __launch_bounds__(256) void f32_to_bf16(
    const float* __restrict__ src, unsigned short* __restrict__ dst, int n4)
{
    const int i = blockIdx.x * 256 + threadIdx.x;
    if (i >= n4) return;
    float4 v = reinterpret_cast<const float4*>(src)[i];
    ushort4 o;
    o.x = f2b(v.x); o.y = f2b(v.y); o.z = f2b(v.z); o.w = f2b(v.w);
    reinterpret_cast<ushort4*>(dst)[i] = o;
}

// all x slices: x [B][T][XD] fp32 -> xball [T][B][XD] bf16 (row = t*B+b)
__global__ __launch_bounds__(256) void conv_x_all(
    const float* __restrict__ x, unsigned short* __restrict__ xball)
{
    const int i = blockIdx.x * 256 + threadIdx.x;   // < B_*T_*XD/4
    const int d = i & 63;                           // float4 within row
    const int bt = i >> 6;
    const int b = bt / T_, t = bt % T_;
    float4 v = reinterpret_cast<const float4*>(x)[i];
    ushort4 o;
    o.x = f2b(v.x); o.y = f2b(v.y); o.z = f2b(v.z); o.w = f2b(v.w);
    reinterpret_cast<ushort4*>(xball)[((size_t)t * B_ + b) * (XD / 4) + d] = o;
}

// Wub[1024][768] = [Wm1; Wv1] (bf16)
__global__ __launch_bounds__(256) void prep_wu(
    const float* __restrict__ Wm1, const float* __restrict__ Wv1,
    unsigned short* __restrict__ Wub)
{
    const int k = blockIdx.x * 256 + threadIdx.x;   // 0..767
    const int nrow = blockIdx.y;                    // 0..1023
    const float v = nrow < 512 ? Wm1[nrow * 768 + k] : Wv1[(nrow - 512) * 768 + k];
    Wub[nrow * 768 + k] = f2b(v);
}

// gate-interleaved reorder of W_ih, W_hh
__global__ __launch_bounds__(256) void prep_wg(
    const float* __restrict__ Wih, const float* __restrict__ Whh,
    unsigned short* __restrict__ Wrih, unsigned short* __restrict__ Wrhh)
{
    const int cc = blockIdx.y;                      // 0..2047
    const int gate = (cc >> 4) & 3;
    const int n = ((cc >> 6) << 4) + (cc & 15);
    const int orig = gate * 512 + n;
    const int kk = blockIdx.x * 256 + threadIdx.x;  // 0..1535
    if (kk < 1024) Wrih[(size_t)cc * 1024 + kk] = f2b(Wih[(size_t)orig * 1024 + kk]);
    else           Wrhh[(size_t)cc * 512 + (kk - 1024)] = f2b(Whh[(size_t)orig * 512 + (kk - 1024)]);
}

// At[k][j] = bf16(A[j][k])  (A is [384][384] fp32 row-major)
__global__ __launch_bounds__(256) void prep_at(
    const float* __restrict__ A, unsigned short* __restrict__ At)
{
    const int i = blockIdx.x * 256 + threadIdx.x;   // 384*384
    const int k = i / DD, j = i % DD;
    At[(size_t)k * DD + j] = f2b(A[(size_t)j * DD + k]);
}

__global__ __launch_bounds__(256) void prep_bias(
    const float* __restrict__ bm1, const float* __restrict__ bv1,
    const float* __restrict__ bih, const float* __restrict__ bhh,
    float* __restrict__ bu, float* __restrict__ br)
{
    const int i = blockIdx.x * 256 + threadIdx.x;   // 0..4095
    if (i < 1024) {
        bu[i] = i < 512 ? bm1[i] : bv1[i - 512];
    } else if (i >= 2048) {
        const int cb = i - 2048;
        const int gate = (cb >> 4) & 3;
        const int n = ((cb >> 6) << 4) + (cb & 15);
        const int orig = gate * 512 + n;
        br[cb] = bih[orig] + bhh[orig];
    }
}

extern "C" void kernel_launch(void* const* d_in, const int* in_sizes, int n_in,
                              void* d_out, int out_size, void* d_ws, size_t ws_size,
                              hipStream_t stream)
{
    const float* x    = (const float*)d_in[0];
    const float* A    = (const float*)d_in[3];
    const float* Wm1  = (const float*)d_in[4];
    const float* bm1  = (const float*)d_in[5];
    const float* Wm2  = (const float*)d_in[6];
    const float* bm2  = (const float*)d_in[7];
    const float* Wv1  = (const float*)d_in[8];
    const float* bv1  = (const float*)d_in[9];
    const float* Wv2  = (const float*)d_in[10];
    const float* bv2  = (const float*)d_in[11];
    const float* Wphi = (const float*)d_in[12];
    const float* bphi = (const float*)d_in[13];
    const float* W_ih = (const float*)d_in[14];
    const float* W_hh = (const float*)d_in[15];
    const float* b_ih = (const float*)d_in[16];
    const float* b_hh = (const float*)d_in[17];

    float* out = (float*)d_out;
    float* out_z    = out;
    float* out_mean = out_z + (size_t)B_ * T_ * ZD;
    float* out_lv   = out_mean + (size_t)B_ * T_ * ZD;
    float* out_hout = out_lv + (size_t)B_ * T_ * ZD;
    float* out_hlo  = out_hout + (size_t)B_ * T_ * HD;

    // ---- workspace layout (~255 MB) ----
    char* wp = (char*)d_ws;
    auto alloc_f = [&](size_t n) { float* p = (float*)wp; wp += n * sizeof(float); return p; };
    auto alloc_b = [&](size_t n) { unsigned short* p = (unsigned short*)wp; wp += n * sizeof(unsigned short); return p; };

    float* c = alloc_f((size_t)B_ * HD);
    unsigned short* hb0     = alloc_b((size_t)B_ * HD);
    unsigned short* hb1     = alloc_b((size_t)B_ * HD);
    unsigned short* xball   = alloc_b((size_t)T_ * B_ * XD);
    unsigned short* umuvall = alloc_b((size_t)T_ * B_ * 1024);
    unsigned short* phib    = alloc_b((size_t)B_ * 1024);

    unsigned short* Wub   = alloc_b((size_t)1024 * 768);
    unsigned short* Wm2b  = alloc_b((size_t)ZD * HD);
    unsigned short* Wv2b  = alloc_b((size_t)ZD * HD);
    unsigned short* Atb   = alloc_b((size_t)DD * DD);
    unsigned short* Wphib = alloc_b((size_t)1024 * DD);
    unsigned short* Wcb   = alloc_b((size_t)1024 * DD);
    unsigned short* Wrih  = alloc_b((size_t)2048 * 1024);
    unsigned short* Wrhh  = alloc_b((size_t)2048 * 512);

    float* bu = alloc_f(1024);
    float* br = alloc_f(2048);

    const dim3 blk(256);

    // ---- prep (once per call) ----
    init_state<<<dim3(B_ * HD / 256), blk, 0, stream>>>(c, hb0, out_hout);
    conv_x_all<<<dim3(B_ * T_ * XD / 4 / 256), blk, 0, stream>>>(x, xball);
    prep_wu<<<dim3(3, 1024), blk, 0, stream>>>(Wm1, Wv1, Wub);
    f32_to_bf16<<<dim3(ZD * HD / 4 / 256), blk, 0, stream>>>(Wm2, Wm2b, ZD * HD / 4);
    f32_to_bf16<<<dim3(ZD * HD / 4 / 256), blk, 0, stream>>>(Wv2, Wv2b, ZD * HD / 4);
    prep_wg<<<dim3(6, 2048), blk, 0, stream>>>(W_ih, W_hh, Wrih, Wrhh);
    prep_bias<<<dim3(16), blk, 0, stream>>>(bm1, bv1, b_ih, b_hh, bu, br);
    prep_at<<<dim3(DD * DD / 256), blk, 0, stream>>>(A, Atb);
    f32_to_bf16<<<dim3(1024 * DD / 4 / 256), blk, 0, stream>>>(Wphi, Wphib, 1024 * DD / 4);
    // Wc = Wphi @ A  ([1024 x 384] bf16): folds the agg GEMM into phi
    k_gemm_plain<<<dim3(DD / 128, 1024 / 128), blk, 0, stream>>>(
        Wphib, DD, DD, Atb, DD, Wcb, DD);

    for (int t = 0; t < T_; ++t) {
        unsigned short* hbt = (t & 1) ? hb1 : hb0;   // h_t  (read)
        unsigned short* hbn = (t & 1) ? hb0 : hb1;   // h_{t+1} (written by epilogue)
        const unsigned short* xb = xball + (size_t)t * B_ * XD;
        unsigned short* uslot = umuvall + (size_t)t * B_ * 1024;

        // [u_m | u_v] = lrelu([x_t, h] @ Wub^T + bu)   [B, 1024]  MT=64, grid 512
        k_gemm_act<1, 64, 7, 3><<<dim3(512), blk, 0, stream>>>(
            xb, XD, XD, hbt, HD, HD,
            Wub, XD + HD, Wub + XD, XD + HD,
            bu, uslot, 1024);

        // mean (in-LDS) + phi fused; bn==0 writes out_z/out_mean
        k_meanphi<<<dim3(512), blk, 0, stream>>>(
            uslot, xb, Wm2b, Wcb, bm2, bphi,
            out_z + (size_t)t * ZD, out_mean + (size_t)t * ZD, phib);

        // gates (reordered) + fused LSTM   MT=128, grid 512, XCD-swizzled
        k_gates_lstm<<<dim3(512), blk, 0, stream>>>(
            phib, hbt, Wrih, Wrhh, br,
            c, hbn,
            out_hlo + (size_t)t * HD,
            (t + 1 < T_) ? out_hout + (size_t)(t + 1) * HD : nullptr);
    }

    // logvar for ALL steps in one batched GEMM (off the recurrence path)
    k_logvar_all<<<dim3(T_ * B_ / 64), blk, 0, stream>>>(
        umuvall, Wv2b, bv2, out_lv);
}